// Round 3
// baseline (361.829 us; speedup 1.0000x reference)
//
#include <hip/hip_runtime.h>

// LSTM B=8192, T=512, I=1, H=32; out[b] = h_T . W_lin + b_lin.  All I/O f32.
//
// R16 (resubmit; R2 bench was an infra double-failure, no kernel signal).
// LANE-LOCAL recurrence. One wave = one 16-batch group, all 32 hiddens,
// 8 MFMAs/step with custom A-tiles phi(m): MFMA m row rho=4a+r -> W_hh gate
// row [32r + 8a + m], so lane(q,col) acc[m] slots = gates i,f,g,o of hidden
// 8q+m. Over m=0..7 the lane owns h[8q..8q+7] of batch col == exactly its
// B-frag slots (k=8q..8q+7) for the next step's MFMA. Recurrence needs NO
// LDS exchange and NO barrier: pack 8 h's via 4x cvt_pkrtz -> bfrag.
//
// Why: R13 wall 801 = P(~530 latency: barrier 80 + ds_read 130 + mfma 25 +
// act chain 120 + drain/skew) + I(273 issue). R15 confirmed model (P 460 +
// I 664 = 1125 measured). Lane-local kills the exchange terms of P (~60
// left, hidden under 4 independent act chains) and ~35% of issue. Cost:
// 512 waves = 2/CU -> half the SIMDs idle; wall = per-wave issue ~700-730.
// Predict ~150 us. Activation math identical to R13 (paired rcp, pkrtz).
// NOTE: packed f32x2 (v_pk_*) acts failed post-timing determinism in R12 -
// do not reintroduce.
//
// Ledger (dur_us): dot2-VALU 490 -> mfma 1-wave 360 -> 2-wave 297 -> 4-wave
// trans-split 215 -> 8-wave custom 190 -> 4-wave custom 171/179 -> R15
// dual-wave-group 240 (FAILED: wall=P+I, 1 wave/SIMD removed free bubble
// filler) -> this.

#define L2E 1.4426950408889634f

typedef _Float16 f16x8 __attribute__((ext_vector_type(8)));
typedef float    f32x4 __attribute__((ext_vector_type(4)));

#define ACT_PAIR(A0, A1, C0, C1, H0, H1, PK)                                          \
    {                                                                                 \
        float ei0 = __builtin_amdgcn_exp2f(-(A0)[0]);                                 \
        float ef0 = __builtin_amdgcn_exp2f(-(A0)[1]);                                 \
        float eg0 = __builtin_amdgcn_exp2f(-(A0)[2]);                                 \
        float eo0 = __builtin_amdgcn_exp2f(-(A0)[3]);                                 \
        float ei1 = __builtin_amdgcn_exp2f(-(A1)[0]);                                 \
        float ef1 = __builtin_amdgcn_exp2f(-(A1)[1]);                                 \
        float eg1 = __builtin_amdgcn_exp2f(-(A1)[2]);                                 \
        float eo1 = __builtin_amdgcn_exp2f(-(A1)[3]);                                 \
        float aI0 = 1.0f + ei0, aF0 = 1.0f + ef0, aG0 = 1.0f + eg0, aO0 = 1.0f + eo0; \
        float aI1 = 1.0f + ei1, aF1 = 1.0f + ef1, aG1 = 1.0f + eg1, aO1 = 1.0f + eo1; \
        float tIG0 = aI0 * aG0, tIG1 = aI1 * aG1;                                     \
        float num0 = fmaf((C0), tIG0, (1.0f - eg0) * aF0);                            \
        float num1 = fmaf((C1), tIG1, (1.0f - eg1) * aF1);                            \
        float D0 = aF0 * tIG0, D1 = aF1 * tIG1;                                       \
        float rD = __builtin_amdgcn_rcpf(D0 * D1);                                    \
        (C0) = num0 * (rD * D1);                                                      \
        (C1) = num1 * (rD * D0);                                                      \
        float ec0 = __builtin_amdgcn_exp2f((C0) * (-2.0f * L2E));                     \
        float ec1 = __builtin_amdgcn_exp2f((C1) * (-2.0f * L2E));                     \
        float Hh0 = aO0 * (1.0f + ec0), Hh1 = aO1 * (1.0f + ec1);                     \
        float rH = __builtin_amdgcn_rcpf(Hh0 * Hh1);                                  \
        (H0) = (1.0f - ec0) * (rH * Hh1);                                             \
        (H1) = (1.0f - ec1) * (rH * Hh0);                                             \
        (PK) = __builtin_bit_cast(unsigned int, __builtin_amdgcn_cvt_pkrtz((H0), (H1))); \
    }

__global__ __launch_bounds__(64, 1) void lstm_ll(
    const float* __restrict__ x,      // [B*512]
    const float* __restrict__ W_ih,   // [128]
    const float* __restrict__ W_hh,   // [128*32]
    const float* __restrict__ b_ih,   // [128]
    const float* __restrict__ b_hh,   // [128]
    const float* __restrict__ W_lin,  // [32]
    const float* __restrict__ b_lin,  // [1]
    float* __restrict__ out)          // [B]
{
    __shared__ float xs[512 * 17];     // x transposed [t][b], stride 17 (34.8 KB)

    const int tid  = threadIdx.x;      // one wave per block
    const int col  = tid & 15;         // batch within group
    const int quad = tid >> 4;         // 0..3: owns hiddens [8quad, 8quad+8)
    const int base = blockIdx.x * 16;  // global batch base

    // ---- stage x[base..base+15][0..511] into LDS transposed ----
    {
        const float4* xg = (const float4*)(x + (size_t)base * 512);
        #pragma unroll 4
        for (int i = 0; i < 32; ++i) {
            int idx = i * 64 + tid;            // 0..2047 float4s
            int b   = idx >> 7;                // batch 0..15
            int tq  = idx & 127;               // float4 within batch row
            float4 v = xg[b * 128 + tq];
            int t0 = tq * 4;
            xs[(t0 + 0) * 17 + b] = v.x;
            xs[(t0 + 1) * 17 + b] = v.y;
            xs[(t0 + 2) * 17 + b] = v.z;
            xs[(t0 + 3) * 17 + b] = v.w;
        }
    }

    // ---- custom A-tiles: MFMA m, A-row rho=4a+r -> W_hh gate-row 32r+8a+m.
    // A-frag layout (R13-verified): lane(quad,col): row=col, k=8*quad+j. ----
    f16x8 wA[8];
    {
        const int r = col & 3;
        const int a = col >> 2;
        const float s = (r == 2) ? (2.0f * L2E) : L2E;
        #pragma unroll
        for (int m = 0; m < 8; ++m) {
            const int grow = 32 * r + 8 * a + m;
            #pragma unroll
            for (int j = 0; j < 8; ++j)
                wA[m][j] = (_Float16)(W_hh[grow * 32 + quad * 8 + j] * s);
        }
    }

    // C-init constants: acc[m] slot r = gate r of hidden 8*quad+m
    float wih[8][4], bia[8][4];
    #pragma unroll
    for (int m = 0; m < 8; ++m)
        #pragma unroll
        for (int r = 0; r < 4; ++r) {
            const float s = (r == 2) ? (2.0f * L2E) : L2E;
            const int g = 32 * r + 8 * quad + m;
            wih[m][r] = W_ih[g] * s;
            bia[m][r] = (b_ih[g] + b_hh[g]) * s;
        }

    __syncthreads();

    float cc[8] = {0.f, 0.f, 0.f, 0.f, 0.f, 0.f, 0.f, 0.f};
    float hl[8];
    f16x8 bfrag = {};                  // h = 0
    f32x4 cq[8];
    {
        float xt = xs[col];            // t = 0
        #pragma unroll
        for (int m = 0; m < 8; ++m)
            #pragma unroll
            for (int r = 0; r < 4; ++r)
                cq[m][r] = fmaf(xt, wih[m][r], bia[m][r]);
    }

    for (int t = 0; t < 512; ++t) {
        f32x4 a0 = __builtin_amdgcn_mfma_f32_16x16x32_f16(wA[0], bfrag, cq[0], 0, 0, 0);
        f32x4 a1 = __builtin_amdgcn_mfma_f32_16x16x32_f16(wA[1], bfrag, cq[1], 0, 0, 0);
        f32x4 a2 = __builtin_amdgcn_mfma_f32_16x16x32_f16(wA[2], bfrag, cq[2], 0, 0, 0);
        f32x4 a3 = __builtin_amdgcn_mfma_f32_16x16x32_f16(wA[3], bfrag, cq[3], 0, 0, 0);
        f32x4 a4 = __builtin_amdgcn_mfma_f32_16x16x32_f16(wA[4], bfrag, cq[4], 0, 0, 0);
        f32x4 a5 = __builtin_amdgcn_mfma_f32_16x16x32_f16(wA[5], bfrag, cq[5], 0, 0, 0);
        f32x4 a6 = __builtin_amdgcn_mfma_f32_16x16x32_f16(wA[6], bfrag, cq[6], 0, 0, 0);
        f32x4 a7 = __builtin_amdgcn_mfma_f32_16x16x32_f16(wA[7], bfrag, cq[7], 0, 0, 0);

        float xt1 = xs[((t + 1) & 511) * 17 + col];       // prefetch next x

        // fused activations: hiddens 8q+2p, 8q+2p+1 per pair; rcps PAIRED
        unsigned int pk0, pk1, pk2, pk3;
        ACT_PAIR(a0, a1, cc[0], cc[1], hl[0], hl[1], pk0);
        ACT_PAIR(a2, a3, cc[2], cc[3], hl[2], hl[3], pk1);
        ACT_PAIR(a4, a5, cc[4], cc[5], hl[4], hl[5], pk2);
        ACT_PAIR(a6, a7, cc[6], cc[7], hl[6], hl[7], pk3);

        // lane-local B-frag: slot j = h of hidden 8q+j (pairs -> dwords)
        union { f16x8 v; unsigned int u[4]; } bb;
        bb.u[0] = pk0; bb.u[1] = pk1; bb.u[2] = pk2; bb.u[3] = pk3;
        bfrag = bb.v;

        // next step's C-init (independent work; fills trans latency gaps)
        #pragma unroll
        for (int m = 0; m < 8; ++m)
            #pragma unroll
            for (int r = 0; r < 4; ++r)
                cq[m][r] = fmaf(xt1, wih[m][r], bia[m][r]);
    }

    // ---- epilogue: out[b] = sum_j h_j * W_lin[j] + b_lin ----
    float v = 0.0f;
    #pragma unroll
    for (int j = 0; j < 8; ++j)
        v = fmaf(hl[j], W_lin[8 * quad + j], v);
    v += __shfl_xor(v, 16);            // combine quads
    v += __shfl_xor(v, 32);
    if (tid < 16)
        out[base + col] = v + b_lin[0];
}

extern "C" void kernel_launch(void* const* d_in, const int* in_sizes, int n_in,
                              void* d_out, int out_size, void* d_ws, size_t ws_size,
                              hipStream_t stream) {
    const float* x     = (const float*)d_in[0];
    const float* W_ih  = (const float*)d_in[1];
    const float* W_hh  = (const float*)d_in[2];
    const float* b_ih  = (const float*)d_in[3];
    const float* b_hh  = (const float*)d_in[4];
    const float* W_lin = (const float*)d_in[5];
    const float* b_lin = (const float*)d_in[6];
    float* out = (float*)d_out;

    const int B = in_sizes[0] / 512;   // 8192
    dim3 grid(B / 16), block(64);
    lstm_ll<<<grid, block, 0, stream>>>(x, W_ih, W_hh, b_ih, b_hh, W_lin, b_lin, out);
}

// Round 4
// 352.825 us; speedup vs baseline: 1.0255x; 1.0255x over previous
//
#include <hip/hip_runtime.h>

// LSTM B=8192, T=512, I=1, H=32; out[b] = h_T . W_lin + b_lin.  All I/O f32.
//
// R17: lane-local recurrence (R16) + C-init folded into the MATRIX PIPE.
// R16 post-mortem: wall 1467 cyc/step vs static issue ~738. VGPR_Count=132
// vs permanent-live ~150 (wA 32 + wih/bia 64 + cq 32 + cc/hl/bfrag 20) ->
// allocator live-range-split/AGPR-shuffled and the scheduler SERIALIZED the
// 4 ACT_PAIR chains (VALUBusy implies ~1200 VALU cyc/wave/step, +460 unseen)
// exposing 4x ~150cyc trans-chain latency with no co-resident wave to fill.
//
// Fix: cq[m] = x_t*wih + bia is a rank-2 update -> MFMA on the idle matrix
// pipe (MfmaUtil 4.5%). A2 tile rows (k): 0: wih_hi, 1: wih_hi, 2: wih_lo,
// 3: bia_hi, 4: bia_lo; B rows: x_hi, x_lo, x_hi, 1, 1 (split-precision:
// residual error = wih_lo*x_lo ~ 1e-6; bias split kills systematic offset).
// Quads 1-3 contribute B rows k>=8 which multiply ZERO A2 columns -> b2 can
// be built unmasked on all lanes. Deletes wih/bia (64 VGPR) + 32 fma/step;
// adds ~8 VALU + 8 MFMAs/step. wA/wA2 read-only -> AGPR-friendly.
// Predict: VGPR ~170-210, wall ~720-850 -> dur ~155-180 us, VALUBusy 45-50,
// MfmaUtil ~9. If >=250 us: pressure theory wrong -> revert to R13 line.
// NOTE: packed f32x2 (v_pk_*) acts failed post-timing determinism in R12 -
// do not reintroduce.
//
// Ledger (dur_us): dot2-VALU 490 -> mfma 1-wave 360 -> 2-wave 297 -> 4-wave
// trans-split 215 -> 8-wave custom 190 -> 4-wave custom 171/179 -> R15
// dual-wave-group 240 (FAILED: wall=P+I) -> R16 lane-local 313 (FAILED:
// reg-pressure serialized act chains) -> this.

#define L2E 1.4426950408889634f

typedef _Float16 f16x8 __attribute__((ext_vector_type(8)));
typedef float    f32x4 __attribute__((ext_vector_type(4)));

#define ACT_PAIR(A0, A1, C0, C1, H0, H1, PK)                                          \
    {                                                                                 \
        float ei0 = __builtin_amdgcn_exp2f(-(A0)[0]);                                 \
        float ef0 = __builtin_amdgcn_exp2f(-(A0)[1]);                                 \
        float eg0 = __builtin_amdgcn_exp2f(-(A0)[2]);                                 \
        float eo0 = __builtin_amdgcn_exp2f(-(A0)[3]);                                 \
        float ei1 = __builtin_amdgcn_exp2f(-(A1)[0]);                                 \
        float ef1 = __builtin_amdgcn_exp2f(-(A1)[1]);                                 \
        float eg1 = __builtin_amdgcn_exp2f(-(A1)[2]);                                 \
        float eo1 = __builtin_amdgcn_exp2f(-(A1)[3]);                                 \
        float aI0 = 1.0f + ei0, aF0 = 1.0f + ef0, aG0 = 1.0f + eg0, aO0 = 1.0f + eo0; \
        float aI1 = 1.0f + ei1, aF1 = 1.0f + ef1, aG1 = 1.0f + eg1, aO1 = 1.0f + eo1; \
        float tIG0 = aI0 * aG0, tIG1 = aI1 * aG1;                                     \
        float num0 = fmaf((C0), tIG0, (1.0f - eg0) * aF0);                            \
        float num1 = fmaf((C1), tIG1, (1.0f - eg1) * aF1);                            \
        float D0 = aF0 * tIG0, D1 = aF1 * tIG1;                                       \
        float rD = __builtin_amdgcn_rcpf(D0 * D1);                                    \
        (C0) = num0 * (rD * D1);                                                      \
        (C1) = num1 * (rD * D0);                                                      \
        float ec0 = __builtin_amdgcn_exp2f((C0) * (-2.0f * L2E));                     \
        float ec1 = __builtin_amdgcn_exp2f((C1) * (-2.0f * L2E));                     \
        float Hh0 = aO0 * (1.0f + ec0), Hh1 = aO1 * (1.0f + ec1);                     \
        float rH = __builtin_amdgcn_rcpf(Hh0 * Hh1);                                  \
        (H0) = (1.0f - ec0) * (rH * Hh1);                                             \
        (H1) = (1.0f - ec1) * (rH * Hh0);                                             \
        (PK) = __builtin_bit_cast(unsigned int, __builtin_amdgcn_cvt_pkrtz((H0), (H1))); \
    }

__global__ __launch_bounds__(64, 1) void lstm_llb(
    const float* __restrict__ x,      // [B*512]
    const float* __restrict__ W_ih,   // [128]
    const float* __restrict__ W_hh,   // [128*32]
    const float* __restrict__ b_ih,   // [128]
    const float* __restrict__ b_hh,   // [128]
    const float* __restrict__ W_lin,  // [32]
    const float* __restrict__ b_lin,  // [1]
    float* __restrict__ out)          // [B]
{
    __shared__ float xs[512 * 17];     // x transposed [t][b], stride 17 (34.8 KB)

    const int tid  = threadIdx.x;      // one wave per block
    const int col  = tid & 15;         // batch within group
    const int quad = tid >> 4;         // 0..3: owns hiddens [8quad, 8quad+8)
    const int base = blockIdx.x * 16;  // global batch base

    // ---- stage x[base..base+15][0..511] into LDS transposed ----
    {
        const float4* xg = (const float4*)(x + (size_t)base * 512);
        #pragma unroll 4
        for (int i = 0; i < 32; ++i) {
            int idx = i * 64 + tid;            // 0..2047 float4s
            int b   = idx >> 7;                // batch 0..15
            int tq  = idx & 127;               // float4 within batch row
            float4 v = xg[b * 128 + tq];
            int t0 = tq * 4;
            xs[(t0 + 0) * 17 + b] = v.x;
            xs[(t0 + 1) * 17 + b] = v.y;
            xs[(t0 + 2) * 17 + b] = v.z;
            xs[(t0 + 3) * 17 + b] = v.w;
        }
    }

    // ---- main A-tiles: MFMA m, A-row rho=4a+r -> W_hh gate-row 32r+8a+m.
    // A-frag layout (R13-verified): lane(quad,col): row=col, k=8*quad+j. ----
    f16x8 wA[8];
    {
        const int r = col & 3;
        const int a = col >> 2;
        const float s = (r == 2) ? (2.0f * L2E) : L2E;
        #pragma unroll
        for (int m = 0; m < 8; ++m) {
            const int grow = 32 * r + 8 * a + m;
            #pragma unroll
            for (int j = 0; j < 8; ++j)
                wA[m][j] = (_Float16)(W_hh[grow * 32 + quad * 8 + j] * s);
        }
    }

    // ---- bias A2-tiles (C-init MFMA): same row permutation; only k=0..4
    // nonzero -> live in quad-0 lanes (k=8q+j). k: 0 wih_hi, 1 wih_hi,
    // 2 wih_lo, 3 bia_hi, 4 bia_lo.  D slot r (lane q,col) = init of gate r,
    // hidden 8q+m, batch col. ----
    f16x8 wA2[8];
    #pragma unroll
    for (int m = 0; m < 8; ++m) wA2[m] = (f16x8){};
    if (quad == 0) {
        const int r = col & 3;
        const int a = col >> 2;
        const float s = (r == 2) ? (2.0f * L2E) : L2E;
        #pragma unroll
        for (int m = 0; m < 8; ++m) {
            const int g = 32 * r + 8 * a + m;
            const float wih = W_ih[g] * s;
            const float bia = (b_ih[g] + b_hh[g]) * s;
            _Float16 wh = (_Float16)wih;
            _Float16 wl = (_Float16)(wih - (float)wh);
            _Float16 bh = (_Float16)bia;
            _Float16 bl = (_Float16)(bia - (float)bh);
            wA2[m][0] = wh; wA2[m][1] = wh; wA2[m][2] = wl;
            wA2[m][3] = bh; wA2[m][4] = bl;
        }
    }

    __syncthreads();

    const f32x4 fzero = {0.f, 0.f, 0.f, 0.f};
    float cc[8] = {0.f, 0.f, 0.f, 0.f, 0.f, 0.f, 0.f, 0.f};
    float hl[8];
    f16x8 bfrag = {};                  // h = 0
    f32x4 cq[8];
    {
        // t=0 C-init via bias-MFMA: B rows k=0..4 = (x_hi, x_lo, x_hi, 1, 1)
        float xt = xs[col];
        _Float16 xh16 = (_Float16)xt;
        _Float16 xl16 = (_Float16)(xt - (float)xh16);
        f16x8 b2 = {};
        b2[0] = xh16; b2[1] = xl16; b2[2] = xh16;
        b2[3] = (_Float16)1.0f; b2[4] = (_Float16)1.0f;
        #pragma unroll
        for (int m = 0; m < 8; ++m)
            cq[m] = __builtin_amdgcn_mfma_f32_16x16x32_f16(wA2[m], b2, fzero, 0, 0, 0);
    }

    for (int t = 0; t < 512; ++t) {
        f32x4 a0 = __builtin_amdgcn_mfma_f32_16x16x32_f16(wA[0], bfrag, cq[0], 0, 0, 0);
        f32x4 a1 = __builtin_amdgcn_mfma_f32_16x16x32_f16(wA[1], bfrag, cq[1], 0, 0, 0);
        f32x4 a2 = __builtin_amdgcn_mfma_f32_16x16x32_f16(wA[2], bfrag, cq[2], 0, 0, 0);
        f32x4 a3 = __builtin_amdgcn_mfma_f32_16x16x32_f16(wA[3], bfrag, cq[3], 0, 0, 0);
        f32x4 a4 = __builtin_amdgcn_mfma_f32_16x16x32_f16(wA[4], bfrag, cq[4], 0, 0, 0);
        f32x4 a5 = __builtin_amdgcn_mfma_f32_16x16x32_f16(wA[5], bfrag, cq[5], 0, 0, 0);
        f32x4 a6 = __builtin_amdgcn_mfma_f32_16x16x32_f16(wA[6], bfrag, cq[6], 0, 0, 0);
        f32x4 a7 = __builtin_amdgcn_mfma_f32_16x16x32_f16(wA[7], bfrag, cq[7], 0, 0, 0);

        float xt1 = xs[((t + 1) & 511) * 17 + col];       // prefetch next x (ds latency hidden under acts)

        // fused activations: hiddens 8q+2p, 8q+2p+1 per pair; rcps PAIRED;
        // 4 independent chains - scheduler interleaves now that regs are free
        unsigned int pk0, pk1, pk2, pk3;
        ACT_PAIR(a0, a1, cc[0], cc[1], hl[0], hl[1], pk0);
        ACT_PAIR(a2, a3, cc[2], cc[3], hl[2], hl[3], pk1);
        ACT_PAIR(a4, a5, cc[4], cc[5], hl[4], hl[5], pk2);
        ACT_PAIR(a6, a7, cc[6], cc[7], hl[6], hl[7], pk3);

        // next step's C-init on the matrix pipe (needed only next iteration)
        {
            _Float16 xh16 = (_Float16)xt1;
            _Float16 xl16 = (_Float16)(xt1 - (float)xh16);
            f16x8 b2 = {};
            b2[0] = xh16; b2[1] = xl16; b2[2] = xh16;
            b2[3] = (_Float16)1.0f; b2[4] = (_Float16)1.0f;
            #pragma unroll
            for (int m = 0; m < 8; ++m)
                cq[m] = __builtin_amdgcn_mfma_f32_16x16x32_f16(wA2[m], b2, fzero, 0, 0, 0);
        }

        // lane-local B-frag: slot j = h of hidden 8q+j (pairs -> dwords)
        union { f16x8 v; unsigned int u[4]; } bb;
        bb.u[0] = pk0; bb.u[1] = pk1; bb.u[2] = pk2; bb.u[3] = pk3;
        bfrag = bb.v;
    }

    // ---- epilogue: out[b] = sum_j h_j * W_lin[j] + b_lin ----
    float v = 0.0f;
    #pragma unroll
    for (int j = 0; j < 8; ++j)
        v = fmaf(hl[j], W_lin[8 * quad + j], v);
    v += __shfl_xor(v, 16);            // combine quads
    v += __shfl_xor(v, 32);
    if (tid < 16)
        out[base + col] = v + b_lin[0];
}

extern "C" void kernel_launch(void* const* d_in, const int* in_sizes, int n_in,
                              void* d_out, int out_size, void* d_ws, size_t ws_size,
                              hipStream_t stream) {
    const float* x     = (const float*)d_in[0];
    const float* W_ih  = (const float*)d_in[1];
    const float* W_hh  = (const float*)d_in[2];
    const float* b_ih  = (const float*)d_in[3];
    const float* b_hh  = (const float*)d_in[4];
    const float* W_lin = (const float*)d_in[5];
    const float* b_lin = (const float*)d_in[6];
    float* out = (float*)d_out;

    const int B = in_sizes[0] / 512;   // 8192
    dim3 grid(B / 16), block(64);
    lstm_llb<<<grid, block, 0, stream>>>(x, W_ih, W_hh, b_ih, b_hh, W_lin, b_lin, out);
}